// Round 7
// baseline (1212.357 us; speedup 1.0000x reference)
//
#include <hip/hip_runtime.h>
#include <hip/hip_fp16.h>

#define N_NODES 100000
#define N_EDGES 1000000
#define N_GRAPHS 1000
#define EMBED 64
#define OUT_DIM 128
#define BN_EPS 1e-5f
#define NBLK ((N_NODES + 255) / 256)   // 391 scan blocks

// ---------------- one-time structure kernels ----------------

// writes fp32 h and fp16 mirror
__global__ void embed_kernel(const int* __restrict__ nfeat,
                             const float* __restrict__ atom_embed,
                             float4* __restrict__ h4,
                             __half* __restrict__ hh) {
    int idx = blockIdx.x * blockDim.x + threadIdx.x;   // one float4 each
    if (idx >= N_NODES * 16) return;
    int v = idx >> 4, q = idx & 15;
    const float4* ae = (const float4*)atom_embed;
    float4 val = ae[nfeat[v] * 16 + q];
    h4[idx] = val;
    __half2 m0 = __floats2half2_rn(val.x, val.y);
    __half2 m1 = __floats2half2_rn(val.z, val.w);
    uint2 packed;
    packed.x = *(unsigned*)&m0;
    packed.y = *(unsigned*)&m1;
    ((uint2*)hh)[idx] = packed;
}

__global__ void deg_kernel(const int* __restrict__ dst, int* __restrict__ deg) {
    int e = blockIdx.x * blockDim.x + threadIdx.x;
    if (e < N_EDGES) atomicAdd(&deg[dst[e]], 1);
}

__global__ void scan1_kernel(const int* __restrict__ deg, int* __restrict__ bsum) {
    __shared__ int sm[256];
    int v = blockIdx.x * 256 + threadIdx.x;
    sm[threadIdx.x] = (v < N_NODES) ? deg[v] : 0;
    __syncthreads();
    for (int off = 128; off > 0; off >>= 1) {
        if (threadIdx.x < off) sm[threadIdx.x] += sm[threadIdx.x + off];
        __syncthreads();
    }
    if (threadIdx.x == 0) bsum[blockIdx.x] = sm[0];
}

__global__ void scan2_kernel(const int* __restrict__ bsum, int* __restrict__ bpre) {
    __shared__ int sm[512];
    int i = threadIdx.x;
    int orig = (i < NBLK) ? bsum[i] : 0;
    sm[i] = orig;
    __syncthreads();
    for (int off = 1; off < 512; off <<= 1) {
        int val = sm[i];
        if (i >= off) val += sm[i - off];
        __syncthreads();
        sm[i] = val;
        __syncthreads();
    }
    if (i < NBLK) bpre[i] = sm[i] - orig;   // exclusive prefix of block sums
}

__global__ void scan3_kernel(const int* __restrict__ deg, const int* __restrict__ bpre,
                             int* __restrict__ rowptr, int* __restrict__ cursor) {
    __shared__ int sm[256];
    int v = blockIdx.x * 256 + threadIdx.x;
    int d = (v < N_NODES) ? deg[v] : 0;
    sm[threadIdx.x] = d;
    __syncthreads();
    for (int off = 1; off < 256; off <<= 1) {
        int val = sm[threadIdx.x];
        if (threadIdx.x >= off) val += sm[threadIdx.x - off];
        __syncthreads();
        sm[threadIdx.x] = val;
        __syncthreads();
    }
    if (v < N_NODES) {
        int ex = bpre[blockIdx.x] + sm[threadIdx.x] - d;  // exclusive scan
        rowptr[v] = ex;
        cursor[v] = ex;
    }
    if (v == 0) rowptr[N_NODES] = N_EDGES;
}

// bucket edges by dst; payload packs src (20 bits) + efeat (bits 20+)
__global__ void scatter_kernel(const int* __restrict__ src, const int* __restrict__ dst,
                               const int* __restrict__ efeat,
                               int* __restrict__ cursor, unsigned* __restrict__ ebuf) {
    int e = blockIdx.x * blockDim.x + threadIdx.x;
    if (e >= N_EDGES) return;
    int t = dst[e];
    int pos = atomicAdd(&cursor[t], 1);
    ebuf[pos] = (unsigned)src[e] | ((unsigned)efeat[e] << 20);
}

// graph_ids is sorted: find segment boundaries. gstart has N_GRAPHS+1 entries.
__global__ void gbound_kernel(const int* __restrict__ gid, int* __restrict__ gstart) {
    int v = blockIdx.x * blockDim.x + threadIdx.x;
    if (v > N_NODES) return;
    int cur  = (v < N_NODES) ? gid[v] : N_GRAPHS;
    int prev = (v == 0) ? -1 : gid[v - 1];
    for (int g = prev + 1; g <= cur; ++g) gstart[g] = v;
}

// ---------------- per-layer fused conv ----------------
// R7: lane-per-dim, wave per node (s,b wave-uniform -> one coalesced 128B
// request per gather), 4-deep edge unroll for MLP, LOW VGPR to restore
// occupancy (R6 post-mortem: gather is outstanding-request-bound; 3.4
// resident waves/CU was the limiter, not bytes). GEMM: 4 nodes staged in
// LDS, W read amortized 4x, t read as wave-uniform float4 broadcasts.
__launch_bounds__(256)
__global__ void fused_conv_kernel(const int* __restrict__ rowptr,
                                  const unsigned* __restrict__ ebuf,
                                  const float* __restrict__ bond,   // [5,64]
                                  const __half* __restrict__ hh,    // fp16 mirror
                                  const float* __restrict__ hmast,  // fp32 master
                                  const float* __restrict__ W,      // [64,64]
                                  const float* __restrict__ bias,   // [64]
                                  float* __restrict__ h_pre,
                                  float* __restrict__ colsum,
                                  float* __restrict__ colsq) {
    __shared__ float Ws[EMBED * EMBED];      // 16 KB
    __shared__ float bond_s[5 * EMBED];      // 1.25 KB
    __shared__ float tslab[4][4][EMBED];     // 4 KB: [wave][node][dim]; reused for BN red

    int lane = threadIdx.x & 63;
    int wblk = threadIdx.x >> 6;

    for (int i = threadIdx.x; i < EMBED * EMBED; i += 256) Ws[i] = W[i];
    for (int i = threadIdx.x; i < 5 * EMBED; i += 256) bond_s[i] = bond[i];
    __syncthreads();

    float bj = bias[lane];
    float lsum = 0.0f, lsq = 0.0f;

    int gwid = blockIdx.x * 4 + wblk;       // global wave id
    int nw   = gridDim.x * 4;

    for (int v0 = gwid * 4; v0 < N_NODES; v0 += nw * 4) {
        // ---- gather phase: wave per node, 4 edges in flight ----
#pragma unroll
        for (int k = 0; k < 4; ++k) {
            int v = v0 + k;
            if (v < N_NODES) {
                int rb = rowptr[v], re = rowptr[v + 1];
                float acc = 0.0f;
                int e = rb;
                for (; e + 4 <= re; e += 4) {
                    // consecutive -> compiler merges to dwordx4
                    unsigned p0 = ebuf[e + 0];
                    unsigned p1 = ebuf[e + 1];
                    unsigned p2 = ebuf[e + 2];
                    unsigned p3 = ebuf[e + 3];
                    __half g0 = hh[(size_t)(p0 & 0xFFFFFu) * EMBED + lane];
                    __half g1 = hh[(size_t)(p1 & 0xFFFFFu) * EMBED + lane];
                    __half g2 = hh[(size_t)(p2 & 0xFFFFFu) * EMBED + lane];
                    __half g3 = hh[(size_t)(p3 & 0xFFFFFu) * EMBED + lane];
                    acc += fmaxf(__half2float(g0) + bond_s[(p0 >> 20) * EMBED + lane], 0.f);
                    acc += fmaxf(__half2float(g1) + bond_s[(p1 >> 20) * EMBED + lane], 0.f);
                    acc += fmaxf(__half2float(g2) + bond_s[(p2 >> 20) * EMBED + lane], 0.f);
                    acc += fmaxf(__half2float(g3) + bond_s[(p3 >> 20) * EMBED + lane], 0.f);
                }
                for (; e < re; ++e) {
                    unsigned p = ebuf[e];
                    __half g = hh[(size_t)(p & 0xFFFFFu) * EMBED + lane];
                    acc += fmaxf(__half2float(g) + bond_s[(p >> 20) * EMBED + lane], 0.f);
                }
                float inv = 1.0f / fmaxf((float)(re - rb), 1.0f);
                tslab[wblk][k][lane] = acc * inv + hmast[(size_t)v * EMBED + lane];
            } else {
                tslab[wblk][k][lane] = 0.0f;
            }
        }

        // ---- GEMM phase: 4 nodes share each Ws read ----
        float o0 = bj, o1 = bj, o2 = bj, o3 = bj;
#pragma unroll
        for (int dq = 0; dq < 16; ++dq) {
            float w0 = Ws[(dq * 4 + 0) * EMBED + lane];
            float w1 = Ws[(dq * 4 + 1) * EMBED + lane];
            float w2 = Ws[(dq * 4 + 2) * EMBED + lane];
            float w3 = Ws[(dq * 4 + 3) * EMBED + lane];
            float4 t0 = *(const float4*)&tslab[wblk][0][dq * 4];   // wave-uniform broadcast
            float4 t1 = *(const float4*)&tslab[wblk][1][dq * 4];
            float4 t2 = *(const float4*)&tslab[wblk][2][dq * 4];
            float4 t3 = *(const float4*)&tslab[wblk][3][dq * 4];
            o0 += t0.x * w0 + t0.y * w1 + t0.z * w2 + t0.w * w3;
            o1 += t1.x * w0 + t1.y * w1 + t1.z * w2 + t1.w * w3;
            o2 += t2.x * w0 + t2.y * w1 + t2.z * w2 + t2.w * w3;
            o3 += t3.x * w0 + t3.y * w1 + t3.z * w2 + t3.w * w3;
        }
        float oo[4] = {o0, o1, o2, o3};
#pragma unroll
        for (int k = 0; k < 4; ++k) {
            int vv = v0 + k;
            if (vv < N_NODES) {
                h_pre[(size_t)vv * EMBED + lane] = oo[k];
                lsum += oo[k];
                lsq  += oo[k] * oo[k];
            }
        }
    }

    // BN partial reduction; reuse tslab (each wave writes only its own slice)
    __syncthreads();
    tslab[wblk][0][lane] = lsum;
    tslab[wblk][1][lane] = lsq;
    __syncthreads();
    if (wblk == 0) {
        float s = tslab[0][0][lane] + tslab[1][0][lane] + tslab[2][0][lane] + tslab[3][0][lane];
        float q = tslab[0][1][lane] + tslab[1][1][lane] + tslab[2][1][lane] + tslab[3][1][lane];
        atomicAdd(&colsum[lane], s);
        atomicAdd(&colsq[lane], q);
    }
}

// batchnorm + optional relu + residual; writes fp32 h and fp16 mirror
__global__ void bn_kernel(const float4* __restrict__ h_pre4,
                          const float* __restrict__ colsum,
                          const float* __restrict__ colsq,
                          const float* __restrict__ gamma,
                          const float* __restrict__ beta,
                          float4* __restrict__ h4,
                          __half* __restrict__ hh,
                          int do_relu) {
    int idx = blockIdx.x * blockDim.x + threadIdx.x;   // one float4
    if (idx >= N_NODES * 16) return;
    int q = idx & 15;            // dims 4q..4q+3
    const float invN = 1.0f / (float)N_NODES;
    float4 p = h_pre4[idx];
    float4 r = h4[idx];
    float o[4] = {p.x, p.y, p.z, p.w};
    float rr[4] = {r.x, r.y, r.z, r.w};
#pragma unroll
    for (int c = 0; c < 4; ++c) {
        int j = q * 4 + c;
        float mu  = colsum[j] * invN;
        float var = colsq[j] * invN - mu * mu;
        float inv = rsqrtf(var + BN_EPS);
        float y = (o[c] - mu) * inv * gamma[j] + beta[j];
        if (do_relu) y = fmaxf(y, 0.0f);
        o[c] = y + rr[c];
    }
    float4 res = {o[0], o[1], o[2], o[3]};
    h4[idx] = res;
    __half2 m0 = __floats2half2_rn(res.x, res.y);
    __half2 m1 = __floats2half2_rn(res.z, res.w);
    uint2 packed;
    packed.x = *(unsigned*)&m0;
    packed.y = *(unsigned*)&m1;
    ((uint2*)hh)[idx] = packed;
}

// one wave per graph: sequential coalesced mean over its node range (gid sorted)
__global__ void pool_kernel(const int* __restrict__ gstart,
                            const float* __restrict__ h,
                            float* __restrict__ gmean) {
    int g    = (blockIdx.x * blockDim.x + threadIdx.x) >> 6;
    int lane = threadIdx.x & 63;
    if (g >= N_GRAPHS) return;
    int b = gstart[g], e = gstart[g + 1];
    float s = 0.0f;
    for (int v = b; v < e; ++v) s += h[v * EMBED + lane];
    gmean[g * EMBED + lane] = s / fmaxf((float)(e - b), 1.0f);
}

// [1000,64] @ [64,128] + b, one block (128 threads) per graph
__global__ void pred_kernel(const float* __restrict__ gmean,
                            const float* __restrict__ W,   // [64,128]
                            const float* __restrict__ b,   // [128]
                            float* __restrict__ out) {
    __shared__ float gm[EMBED];
    int g = blockIdx.x;
    int j = threadIdx.x;  // 0..127
    if (j < EMBED) gm[j] = gmean[g * EMBED + j];
    __syncthreads();
    float acc = b[j];
#pragma unroll
    for (int d = 0; d < EMBED; ++d)
        acc += gm[d] * W[d * OUT_DIM + j];
    out[g * OUT_DIM + j] = acc;
}

// ---------------- launch ----------------

extern "C" void kernel_launch(void* const* d_in, const int* in_sizes, int n_in,
                              void* d_out, int out_size, void* d_ws, size_t ws_size,
                              hipStream_t stream) {
    const int*   nfeat      = (const int*)d_in[0];
    const int*   efeat      = (const int*)d_in[1];
    const int*   src        = (const int*)d_in[2];
    const int*   dst        = (const int*)d_in[3];
    const int*   gid        = (const int*)d_in[4];
    const float* atom_embed = (const float*)d_in[5];
    const float* bond_embed = (const float*)d_in[6];  // [3,5,64]
    const float* conv_W     = (const float*)d_in[7];  // [3,64,64]
    const float* conv_b     = (const float*)d_in[8];  // [3,64]
    const float* bn_gamma   = (const float*)d_in[9];  // [3,64]
    const float* bn_beta    = (const float*)d_in[10]; // [3,64]
    const float* pred_W     = (const float*)d_in[11]; // [64,128]
    const float* pred_b     = (const float*)d_in[12]; // [128]
    float* out = (float*)d_out;

    char* wsb = (char*)d_ws;
    float*    h      = (float*)wsb;                     wsb += (size_t)N_NODES * EMBED * 4;
    float*    h_pre  = (float*)wsb;                     wsb += (size_t)N_NODES * EMBED * 4;
    __half*   hh     = (__half*)wsb;                    wsb += (size_t)N_NODES * EMBED * 2;
    int*      deg    = (int*)wsb;                       wsb += (size_t)N_NODES * 4;
    int*      rowptr = (int*)wsb;                       wsb += (size_t)(N_NODES + 1) * 4;
    int*      cursor = (int*)wsb;                       wsb += (size_t)N_NODES * 4;
    int*      bsum   = (int*)wsb;                       wsb += (size_t)NBLK * 4;
    int*      bpre   = (int*)wsb;                       wsb += (size_t)NBLK * 4;
    unsigned* ebuf   = (unsigned*)wsb;                  wsb += (size_t)N_EDGES * 4;
    int*      gstart = (int*)wsb;                       wsb += (size_t)(N_GRAPHS + 1) * 4;
    float*    gmean  = (float*)wsb;                     wsb += (size_t)N_GRAPHS * EMBED * 4;
    float*    colsum = (float*)wsb;                     wsb += (size_t)3 * EMBED * 4;
    float*    colsq  = (float*)wsb;                     wsb += (size_t)3 * EMBED * 4;

    hipMemsetAsync(deg, 0, N_NODES * sizeof(int), stream);
    hipMemsetAsync(colsum, 0, 6 * EMBED * sizeof(float), stream);  // all 3 layers' stats

    embed_kernel<<<(N_NODES * 16 + 255) / 256, 256, 0, stream>>>(nfeat, atom_embed, (float4*)h, hh);
    deg_kernel<<<(N_EDGES + 255) / 256, 256, 0, stream>>>(dst, deg);
    scan1_kernel<<<NBLK, 256, 0, stream>>>(deg, bsum);
    scan2_kernel<<<1, 512, 0, stream>>>(bsum, bpre);
    scan3_kernel<<<NBLK, 256, 0, stream>>>(deg, bpre, rowptr, cursor);
    scatter_kernel<<<(N_EDGES + 255) / 256, 256, 0, stream>>>(src, dst, efeat, cursor, ebuf);
    gbound_kernel<<<(N_NODES + 256) / 256, 256, 0, stream>>>(gid, gstart);

    for (int i = 0; i < 3; ++i) {
        fused_conv_kernel<<<2048, 256, 0, stream>>>(
            rowptr, ebuf, bond_embed + i * 5 * EMBED, hh, h,
            conv_W + i * EMBED * EMBED, conv_b + i * EMBED,
            h_pre, colsum + i * EMBED, colsq + i * EMBED);
        bn_kernel<<<(N_NODES * 16 + 255) / 256, 256, 0, stream>>>(
            (const float4*)h_pre, colsum + i * EMBED, colsq + i * EMBED,
            bn_gamma + i * EMBED, bn_beta + i * EMBED,
            (float4*)h, hh, (i != 2) ? 1 : 0);
    }

    pool_kernel<<<(N_GRAPHS * 64 + 255) / 256, 256, 0, stream>>>(gstart, h, gmean);
    pred_kernel<<<N_GRAPHS, OUT_DIM, 0, stream>>>(gmean, pred_W, pred_b, out);
}

// Round 8
// 644.001 us; speedup vs baseline: 1.8825x; 1.8825x over previous
//
#include <hip/hip_runtime.h>
#include <hip/hip_fp16.h>

#define N_NODES 100000
#define N_EDGES 1000000
#define N_GRAPHS 1000
#define EMBED 64
#define OUT_DIM 128
#define BN_EPS 1e-5f
#define NBLK ((N_NODES + 255) / 256)   // 391 scan blocks

// ---------------- one-time structure kernels ----------------

// writes fp32 h and fp16 mirror
__global__ void embed_kernel(const int* __restrict__ nfeat,
                             const float* __restrict__ atom_embed,
                             float4* __restrict__ h4,
                             __half* __restrict__ hh) {
    int idx = blockIdx.x * blockDim.x + threadIdx.x;   // one float4 each
    if (idx >= N_NODES * 16) return;
    int v = idx >> 4, q = idx & 15;
    const float4* ae = (const float4*)atom_embed;
    float4 val = ae[nfeat[v] * 16 + q];
    h4[idx] = val;
    __half2 m0 = __floats2half2_rn(val.x, val.y);
    __half2 m1 = __floats2half2_rn(val.z, val.w);
    uint2 packed;
    packed.x = *(unsigned*)&m0;
    packed.y = *(unsigned*)&m1;
    ((uint2*)hh)[idx] = packed;
}

__global__ void deg_kernel(const int* __restrict__ dst, int* __restrict__ deg) {
    int e = blockIdx.x * blockDim.x + threadIdx.x;
    if (e < N_EDGES) atomicAdd(&deg[dst[e]], 1);
}

__global__ void scan1_kernel(const int* __restrict__ deg, int* __restrict__ bsum) {
    __shared__ int sm[256];
    int v = blockIdx.x * 256 + threadIdx.x;
    sm[threadIdx.x] = (v < N_NODES) ? deg[v] : 0;
    __syncthreads();
    for (int off = 128; off > 0; off >>= 1) {
        if (threadIdx.x < off) sm[threadIdx.x] += sm[threadIdx.x + off];
        __syncthreads();
    }
    if (threadIdx.x == 0) bsum[blockIdx.x] = sm[0];
}

__global__ void scan2_kernel(const int* __restrict__ bsum, int* __restrict__ bpre) {
    __shared__ int sm[512];
    int i = threadIdx.x;
    int orig = (i < NBLK) ? bsum[i] : 0;
    sm[i] = orig;
    __syncthreads();
    for (int off = 1; off < 512; off <<= 1) {
        int val = sm[i];
        if (i >= off) val += sm[i - off];
        __syncthreads();
        sm[i] = val;
        __syncthreads();
    }
    if (i < NBLK) bpre[i] = sm[i] - orig;   // exclusive prefix of block sums
}

__global__ void scan3_kernel(const int* __restrict__ deg, const int* __restrict__ bpre,
                             int* __restrict__ rowptr, int* __restrict__ cursor) {
    __shared__ int sm[256];
    int v = blockIdx.x * 256 + threadIdx.x;
    int d = (v < N_NODES) ? deg[v] : 0;
    sm[threadIdx.x] = d;
    __syncthreads();
    for (int off = 1; off < 256; off <<= 1) {
        int val = sm[threadIdx.x];
        if (threadIdx.x >= off) val += sm[threadIdx.x - off];
        __syncthreads();
        sm[threadIdx.x] = val;
        __syncthreads();
    }
    if (v < N_NODES) {
        int ex = bpre[blockIdx.x] + sm[threadIdx.x] - d;  // exclusive scan
        rowptr[v] = ex;
        cursor[v] = ex;
    }
    if (v == 0) rowptr[N_NODES] = N_EDGES;
}

// bucket edges by dst; payload packs src (20 bits) + efeat (bits 20+)
__global__ void scatter_kernel(const int* __restrict__ src, const int* __restrict__ dst,
                               const int* __restrict__ efeat,
                               int* __restrict__ cursor, unsigned* __restrict__ ebuf) {
    int e = blockIdx.x * blockDim.x + threadIdx.x;
    if (e >= N_EDGES) return;
    int t = dst[e];
    int pos = atomicAdd(&cursor[t], 1);
    ebuf[pos] = (unsigned)src[e] | ((unsigned)efeat[e] << 20);
}

// graph_ids is sorted: find segment boundaries. gstart has N_GRAPHS+1 entries.
__global__ void gbound_kernel(const int* __restrict__ gid, int* __restrict__ gstart) {
    int v = blockIdx.x * blockDim.x + threadIdx.x;
    if (v > N_NODES) return;
    int cur  = (v < N_NODES) ? gid[v] : N_GRAPHS;
    int prev = (v == 0) ? -1 : gid[v - 1];
    for (int g = prev + 1; g <= cur; ++g) gstart[g] = v;
}

// ---------------- per-layer kernels ----------------

// R8 gather: register-minimal. Wave per node, lane = dim (fp16 -> one
// coalesced 128B request per edge). 4 interleaved edge chains give 4
// independent requests in flight per wave. High occupancy is the goal:
// R6/R7 showed the gather is bound by (resident waves x requests in flight).
__launch_bounds__(256, 4)
__global__ void gather_kernel(const int* __restrict__ rowptr,
                              const unsigned* __restrict__ ebuf,
                              const float* __restrict__ bond,    // [5,64]
                              const __half* __restrict__ hh,     // fp16 mirror
                              const float* __restrict__ hmast,   // fp32 master
                              float* __restrict__ t_out) {
    __shared__ float bond_s[5 * EMBED];
    for (int i = threadIdx.x; i < 5 * EMBED; i += 256) bond_s[i] = bond[i];
    __syncthreads();

    int lane = threadIdx.x & 63;
    int gwid = (blockIdx.x * 256 + threadIdx.x) >> 6;
    int nw   = (gridDim.x * 256) >> 6;

    for (int v = gwid; v < N_NODES; v += nw) {
        int rb = rowptr[v], re = rowptr[v + 1];
        float a0 = 0.f, a1 = 0.f, a2 = 0.f, a3 = 0.f;
        int e = rb;
        for (; e + 4 <= re; e += 4) {
            unsigned p0 = ebuf[e + 0];
            unsigned p1 = ebuf[e + 1];
            unsigned p2 = ebuf[e + 2];
            unsigned p3 = ebuf[e + 3];
            // 4 independent 128B gathers in flight
            float g0 = __half2float(hh[(size_t)(p0 & 0xFFFFFu) * EMBED + lane]);
            float g1 = __half2float(hh[(size_t)(p1 & 0xFFFFFu) * EMBED + lane]);
            float g2 = __half2float(hh[(size_t)(p2 & 0xFFFFFu) * EMBED + lane]);
            float g3 = __half2float(hh[(size_t)(p3 & 0xFFFFFu) * EMBED + lane]);
            a0 += fmaxf(g0 + bond_s[(p0 >> 20) * EMBED + lane], 0.f);
            a1 += fmaxf(g1 + bond_s[(p1 >> 20) * EMBED + lane], 0.f);
            a2 += fmaxf(g2 + bond_s[(p2 >> 20) * EMBED + lane], 0.f);
            a3 += fmaxf(g3 + bond_s[(p3 >> 20) * EMBED + lane], 0.f);
        }
        for (; e < re; ++e) {
            unsigned p = ebuf[e];
            float g = __half2float(hh[(size_t)(p & 0xFFFFFu) * EMBED + lane]);
            a0 += fmaxf(g + bond_s[(p >> 20) * EMBED + lane], 0.f);
        }
        float s = (a0 + a1) + (a2 + a3);
        float inv = 1.0f / fmaxf((float)(re - rb), 1.0f);
        t_out[(size_t)v * EMBED + lane] = s * inv + hmast[(size_t)v * EMBED + lane];
    }
}

// Streaming GEMM + BN column stats: h_pre = t @ W + b. 4 nodes per wave
// staged through LDS; each Ws read amortized over 4 nodes.
__launch_bounds__(256)
__global__ void gemm_kernel(const float* __restrict__ t_in,
                            const float* __restrict__ W,      // [64,64]
                            const float* __restrict__ bias,   // [64]
                            float* __restrict__ h_pre,
                            float* __restrict__ colsum,
                            float* __restrict__ colsq) {
    __shared__ float Ws[EMBED * EMBED];      // 16 KB
    __shared__ float tslab[4][4][EMBED];     // 4 KB; reused for BN reduction

    int lane = threadIdx.x & 63;
    int wblk = threadIdx.x >> 6;

    for (int i = threadIdx.x; i < EMBED * EMBED; i += 256) Ws[i] = W[i];
    __syncthreads();

    float bj = bias[lane];
    float lsum = 0.0f, lsq = 0.0f;

    int gwid = blockIdx.x * 4 + wblk;
    int nw   = gridDim.x * 4;

    for (int v0 = gwid * 4; v0 < N_NODES; v0 += nw * 4) {
#pragma unroll
        for (int k = 0; k < 4; ++k) {
            int v = v0 + k;
            tslab[wblk][k][lane] = (v < N_NODES) ? t_in[(size_t)v * EMBED + lane] : 0.0f;
        }

        float o0 = bj, o1 = bj, o2 = bj, o3 = bj;
#pragma unroll
        for (int dq = 0; dq < 16; ++dq) {
            float w0 = Ws[(dq * 4 + 0) * EMBED + lane];
            float w1 = Ws[(dq * 4 + 1) * EMBED + lane];
            float w2 = Ws[(dq * 4 + 2) * EMBED + lane];
            float w3 = Ws[(dq * 4 + 3) * EMBED + lane];
            float4 t0 = *(const float4*)&tslab[wblk][0][dq * 4];   // wave-uniform broadcast
            float4 t1 = *(const float4*)&tslab[wblk][1][dq * 4];
            float4 t2 = *(const float4*)&tslab[wblk][2][dq * 4];
            float4 t3 = *(const float4*)&tslab[wblk][3][dq * 4];
            o0 += t0.x * w0 + t0.y * w1 + t0.z * w2 + t0.w * w3;
            o1 += t1.x * w0 + t1.y * w1 + t1.z * w2 + t1.w * w3;
            o2 += t2.x * w0 + t2.y * w1 + t2.z * w2 + t2.w * w3;
            o3 += t3.x * w0 + t3.y * w1 + t3.z * w2 + t3.w * w3;
        }
        float oo[4] = {o0, o1, o2, o3};
#pragma unroll
        for (int k = 0; k < 4; ++k) {
            int vv = v0 + k;
            if (vv < N_NODES) {
                h_pre[(size_t)vv * EMBED + lane] = oo[k];
                lsum += oo[k];
                lsq  += oo[k] * oo[k];
            }
        }
    }

    __syncthreads();
    tslab[wblk][0][lane] = lsum;
    tslab[wblk][1][lane] = lsq;
    __syncthreads();
    if (wblk == 0) {
        float s = tslab[0][0][lane] + tslab[1][0][lane] + tslab[2][0][lane] + tslab[3][0][lane];
        float q = tslab[0][1][lane] + tslab[1][1][lane] + tslab[2][1][lane] + tslab[3][1][lane];
        atomicAdd(&colsum[lane], s);
        atomicAdd(&colsq[lane], q);
    }
}

// batchnorm + optional relu + residual; writes fp32 h and fp16 mirror
__global__ void bn_kernel(const float4* __restrict__ h_pre4,
                          const float* __restrict__ colsum,
                          const float* __restrict__ colsq,
                          const float* __restrict__ gamma,
                          const float* __restrict__ beta,
                          float4* __restrict__ h4,
                          __half* __restrict__ hh,
                          int do_relu) {
    int idx = blockIdx.x * blockDim.x + threadIdx.x;   // one float4
    if (idx >= N_NODES * 16) return;
    int q = idx & 15;            // dims 4q..4q+3
    const float invN = 1.0f / (float)N_NODES;
    float4 p = h_pre4[idx];
    float4 r = h4[idx];
    float o[4] = {p.x, p.y, p.z, p.w};
    float rr[4] = {r.x, r.y, r.z, r.w};
#pragma unroll
    for (int c = 0; c < 4; ++c) {
        int j = q * 4 + c;
        float mu  = colsum[j] * invN;
        float var = colsq[j] * invN - mu * mu;
        float inv = rsqrtf(var + BN_EPS);
        float y = (o[c] - mu) * inv * gamma[j] + beta[j];
        if (do_relu) y = fmaxf(y, 0.0f);
        o[c] = y + rr[c];
    }
    float4 res = {o[0], o[1], o[2], o[3]};
    h4[idx] = res;
    __half2 m0 = __floats2half2_rn(res.x, res.y);
    __half2 m1 = __floats2half2_rn(res.z, res.w);
    uint2 packed;
    packed.x = *(unsigned*)&m0;
    packed.y = *(unsigned*)&m1;
    ((uint2*)hh)[idx] = packed;
}

// one wave per graph: sequential coalesced mean over its node range (gid sorted)
__global__ void pool_kernel(const int* __restrict__ gstart,
                            const float* __restrict__ h,
                            float* __restrict__ gmean) {
    int g    = (blockIdx.x * blockDim.x + threadIdx.x) >> 6;
    int lane = threadIdx.x & 63;
    if (g >= N_GRAPHS) return;
    int b = gstart[g], e = gstart[g + 1];
    float s = 0.0f;
    for (int v = b; v < e; ++v) s += h[v * EMBED + lane];
    gmean[g * EMBED + lane] = s / fmaxf((float)(e - b), 1.0f);
}

// [1000,64] @ [64,128] + b, one block (128 threads) per graph
__global__ void pred_kernel(const float* __restrict__ gmean,
                            const float* __restrict__ W,   // [64,128]
                            const float* __restrict__ b,   // [128]
                            float* __restrict__ out) {
    __shared__ float gm[EMBED];
    int g = blockIdx.x;
    int j = threadIdx.x;  // 0..127
    if (j < EMBED) gm[j] = gmean[g * EMBED + j];
    __syncthreads();
    float acc = b[j];
#pragma unroll
    for (int d = 0; d < EMBED; ++d)
        acc += gm[d] * W[d * OUT_DIM + j];
    out[g * OUT_DIM + j] = acc;
}

// ---------------- launch ----------------

extern "C" void kernel_launch(void* const* d_in, const int* in_sizes, int n_in,
                              void* d_out, int out_size, void* d_ws, size_t ws_size,
                              hipStream_t stream) {
    const int*   nfeat      = (const int*)d_in[0];
    const int*   efeat      = (const int*)d_in[1];
    const int*   src        = (const int*)d_in[2];
    const int*   dst        = (const int*)d_in[3];
    const int*   gid        = (const int*)d_in[4];
    const float* atom_embed = (const float*)d_in[5];
    const float* bond_embed = (const float*)d_in[6];  // [3,5,64]
    const float* conv_W     = (const float*)d_in[7];  // [3,64,64]
    const float* conv_b     = (const float*)d_in[8];  // [3,64]
    const float* bn_gamma   = (const float*)d_in[9];  // [3,64]
    const float* bn_beta    = (const float*)d_in[10]; // [3,64]
    const float* pred_W     = (const float*)d_in[11]; // [64,128]
    const float* pred_b     = (const float*)d_in[12]; // [128]
    float* out = (float*)d_out;

    char* wsb = (char*)d_ws;
    float*    h      = (float*)wsb;                     wsb += (size_t)N_NODES * EMBED * 4;
    float*    h_pre  = (float*)wsb;                     wsb += (size_t)N_NODES * EMBED * 4;
    float*    t_buf  = (float*)wsb;                     wsb += (size_t)N_NODES * EMBED * 4;
    __half*   hh     = (__half*)wsb;                    wsb += (size_t)N_NODES * EMBED * 2;
    int*      deg    = (int*)wsb;                       wsb += (size_t)N_NODES * 4;
    int*      rowptr = (int*)wsb;                       wsb += (size_t)(N_NODES + 1) * 4;
    int*      cursor = (int*)wsb;                       wsb += (size_t)N_NODES * 4;
    int*      bsum   = (int*)wsb;                       wsb += (size_t)NBLK * 4;
    int*      bpre   = (int*)wsb;                       wsb += (size_t)NBLK * 4;
    unsigned* ebuf   = (unsigned*)wsb;                  wsb += (size_t)N_EDGES * 4;
    int*      gstart = (int*)wsb;                       wsb += (size_t)(N_GRAPHS + 1) * 4;
    float*    gmean  = (float*)wsb;                     wsb += (size_t)N_GRAPHS * EMBED * 4;
    float*    colsum = (float*)wsb;                     wsb += (size_t)3 * EMBED * 4;
    float*    colsq  = (float*)wsb;                     wsb += (size_t)3 * EMBED * 4;

    hipMemsetAsync(deg, 0, N_NODES * sizeof(int), stream);
    hipMemsetAsync(colsum, 0, 6 * EMBED * sizeof(float), stream);  // all 3 layers' stats

    embed_kernel<<<(N_NODES * 16 + 255) / 256, 256, 0, stream>>>(nfeat, atom_embed, (float4*)h, hh);
    deg_kernel<<<(N_EDGES + 255) / 256, 256, 0, stream>>>(dst, deg);
    scan1_kernel<<<NBLK, 256, 0, stream>>>(deg, bsum);
    scan2_kernel<<<1, 512, 0, stream>>>(bsum, bpre);
    scan3_kernel<<<NBLK, 256, 0, stream>>>(deg, bpre, rowptr, cursor);
    scatter_kernel<<<(N_EDGES + 255) / 256, 256, 0, stream>>>(src, dst, efeat, cursor, ebuf);
    gbound_kernel<<<(N_NODES + 256) / 256, 256, 0, stream>>>(gid, gstart);

    for (int i = 0; i < 3; ++i) {
        gather_kernel<<<2048, 256, 0, stream>>>(
            rowptr, ebuf, bond_embed + i * 5 * EMBED, hh, h, t_buf);
        gemm_kernel<<<1024, 256, 0, stream>>>(
            t_buf, conv_W + i * EMBED * EMBED, conv_b + i * EMBED,
            h_pre, colsum + i * EMBED, colsq + i * EMBED);
        bn_kernel<<<(N_NODES * 16 + 255) / 256, 256, 0, stream>>>(
            (const float4*)h_pre, colsum + i * EMBED, colsq + i * EMBED,
            bn_gamma + i * EMBED, bn_beta + i * EMBED,
            (float4*)h, hh, (i != 2) ? 1 : 0);
    }

    pool_kernel<<<(N_GRAPHS * 64 + 255) / 256, 256, 0, stream>>>(gstart, h, gmean);
    pred_kernel<<<N_GRAPHS, OUT_DIM, 0, stream>>>(gmean, pred_W, pred_b, out);
}

// Round 9
// 607.898 us; speedup vs baseline: 1.9943x; 1.0594x over previous
//
#include <hip/hip_runtime.h>
#include <hip/hip_fp16.h>

#define N_NODES 100000
#define N_EDGES 1000000
#define N_GRAPHS 1000
#define EMBED 64
#define OUT_DIM 128
#define BN_EPS 1e-5f
#define NBLK ((N_NODES + 255) / 256)   // 391 scan blocks

// ---------------- one-time structure kernels ----------------

// writes fp32 h and fp16 mirror
__global__ void embed_kernel(const int* __restrict__ nfeat,
                             const float* __restrict__ atom_embed,
                             float4* __restrict__ h4,
                             __half* __restrict__ hh) {
    int idx = blockIdx.x * blockDim.x + threadIdx.x;   // one float4 each
    if (idx >= N_NODES * 16) return;
    int v = idx >> 4, q = idx & 15;
    const float4* ae = (const float4*)atom_embed;
    float4 val = ae[nfeat[v] * 16 + q];
    h4[idx] = val;
    __half2 m0 = __floats2half2_rn(val.x, val.y);
    __half2 m1 = __floats2half2_rn(val.z, val.w);
    uint2 packed;
    packed.x = *(unsigned*)&m0;
    packed.y = *(unsigned*)&m1;
    ((uint2*)hh)[idx] = packed;
}

__global__ void deg_kernel(const int* __restrict__ dst, int* __restrict__ deg) {
    int e = blockIdx.x * blockDim.x + threadIdx.x;
    if (e < N_EDGES) atomicAdd(&deg[dst[e]], 1);
}

__global__ void scan1_kernel(const int* __restrict__ deg, int* __restrict__ bsum) {
    __shared__ int sm[256];
    int v = blockIdx.x * 256 + threadIdx.x;
    sm[threadIdx.x] = (v < N_NODES) ? deg[v] : 0;
    __syncthreads();
    for (int off = 128; off > 0; off >>= 1) {
        if (threadIdx.x < off) sm[threadIdx.x] += sm[threadIdx.x + off];
        __syncthreads();
    }
    if (threadIdx.x == 0) bsum[blockIdx.x] = sm[0];
}

__global__ void scan2_kernel(const int* __restrict__ bsum, int* __restrict__ bpre) {
    __shared__ int sm[512];
    int i = threadIdx.x;
    int orig = (i < NBLK) ? bsum[i] : 0;
    sm[i] = orig;
    __syncthreads();
    for (int off = 1; off < 512; off <<= 1) {
        int val = sm[i];
        if (i >= off) val += sm[i - off];
        __syncthreads();
        sm[i] = val;
        __syncthreads();
    }
    if (i < NBLK) bpre[i] = sm[i] - orig;   // exclusive prefix of block sums
}

__global__ void scan3_kernel(const int* __restrict__ deg, const int* __restrict__ bpre,
                             int* __restrict__ rowptr, int* __restrict__ cursor) {
    __shared__ int sm[256];
    int v = blockIdx.x * 256 + threadIdx.x;
    int d = (v < N_NODES) ? deg[v] : 0;
    sm[threadIdx.x] = d;
    __syncthreads();
    for (int off = 1; off < 256; off <<= 1) {
        int val = sm[threadIdx.x];
        if (threadIdx.x >= off) val += sm[threadIdx.x - off];
        __syncthreads();
        sm[threadIdx.x] = val;
        __syncthreads();
    }
    if (v < N_NODES) {
        int ex = bpre[blockIdx.x] + sm[threadIdx.x] - d;  // exclusive scan
        rowptr[v] = ex;
        cursor[v] = ex;
    }
    if (v == 0) rowptr[N_NODES] = N_EDGES;
}

// bucket edges by dst; payload packs src (20 bits) + efeat (bits 20+)
// nontemporal store: random 4B scatter, no reuse before eviction
__global__ void scatter_kernel(const int* __restrict__ src, const int* __restrict__ dst,
                               const int* __restrict__ efeat,
                               int* __restrict__ cursor, unsigned* __restrict__ ebuf) {
    int e = blockIdx.x * blockDim.x + threadIdx.x;
    if (e >= N_EDGES) return;
    int t = dst[e];
    int pos = atomicAdd(&cursor[t], 1);
    unsigned payload = (unsigned)src[e] | ((unsigned)efeat[e] << 20);
    __builtin_nontemporal_store(payload, &ebuf[pos]);
}

// graph_ids is sorted: find segment boundaries. gstart has N_GRAPHS+1 entries.
__global__ void gbound_kernel(const int* __restrict__ gid, int* __restrict__ gstart) {
    int v = blockIdx.x * blockDim.x + threadIdx.x;
    if (v > N_NODES) return;
    int cur  = (v < N_NODES) ? gid[v] : N_GRAPHS;
    int prev = (v == 0) ? -1 : gid[v - 1];
    for (int g = prev + 1; g <= cur; ++g) gstart[g] = v;
}

// ---------------- per-layer kernels ----------------

// R9 gather: HALF-WAVE per node (32 lanes x ushort2 = one 128B segment per
// edge), 4 interleaved edge chains -> 8 independent segment requests in
// flight per wave (2x R8), float2 accumulators keep VGPR low. R6/R8 showed
// the gather is bound by total requests in flight, not bytes.
__launch_bounds__(256)
__global__ void gather_kernel(const int* __restrict__ rowptr,
                              const unsigned* __restrict__ ebuf,
                              const float* __restrict__ bond,    // [5,64]
                              const __half* __restrict__ hh,     // fp16 mirror
                              const float* __restrict__ hmast,   // fp32 master
                              float* __restrict__ t_out) {
    __shared__ float bond_s[5 * EMBED];
    for (int i = threadIdx.x; i < 5 * EMBED; i += 256) bond_s[i] = bond[i];
    __syncthreads();

    int half = (threadIdx.x >> 5) & 1;   // which node of the wave's pair
    int sl   = threadIdx.x & 31;         // ushort2 slot: dims 2sl, 2sl+1
    int d0   = sl * 2;

    int gwid = (blockIdx.x * 256 + threadIdx.x) >> 6;
    int nw   = (gridDim.x * 256) >> 6;
    const unsigned* hh32 = (const unsigned*)hh;    // 2 halves per uint

    for (int v = gwid * 2 + half; v < N_NODES; v += nw * 2) {
        int rb = rowptr[v], re = rowptr[v + 1];
        float2 a0 = {0.f, 0.f}, a1 = {0.f, 0.f}, a2 = {0.f, 0.f}, a3 = {0.f, 0.f};
        int e = rb;
        for (; e + 4 <= re; e += 4) {
            unsigned p0 = ebuf[e + 0];
            unsigned p1 = ebuf[e + 1];
            unsigned p2 = ebuf[e + 2];
            unsigned p3 = ebuf[e + 3];
            // 4 independent 128B-segment gathers in flight (per half-wave)
            unsigned g0 = hh32[(size_t)(p0 & 0xFFFFFu) * 32 + sl];
            unsigned g1 = hh32[(size_t)(p1 & 0xFFFFFu) * 32 + sl];
            unsigned g2 = hh32[(size_t)(p2 & 0xFFFFFu) * 32 + sl];
            unsigned g3 = hh32[(size_t)(p3 & 0xFFFFFu) * 32 + sl];
            float2 f0 = __half22float2(*(const __half2*)&g0);
            float2 f1 = __half22float2(*(const __half2*)&g1);
            float2 f2 = __half22float2(*(const __half2*)&g2);
            float2 f3 = __half22float2(*(const __half2*)&g3);
            const float* c0 = &bond_s[(p0 >> 20) * EMBED + d0];
            const float* c1 = &bond_s[(p1 >> 20) * EMBED + d0];
            const float* c2 = &bond_s[(p2 >> 20) * EMBED + d0];
            const float* c3 = &bond_s[(p3 >> 20) * EMBED + d0];
            a0.x += fmaxf(f0.x + c0[0], 0.f);  a0.y += fmaxf(f0.y + c0[1], 0.f);
            a1.x += fmaxf(f1.x + c1[0], 0.f);  a1.y += fmaxf(f1.y + c1[1], 0.f);
            a2.x += fmaxf(f2.x + c2[0], 0.f);  a2.y += fmaxf(f2.y + c2[1], 0.f);
            a3.x += fmaxf(f3.x + c3[0], 0.f);  a3.y += fmaxf(f3.y + c3[1], 0.f);
        }
        for (; e < re; ++e) {
            unsigned p = ebuf[e];
            unsigned g = hh32[(size_t)(p & 0xFFFFFu) * 32 + sl];
            float2 f = __half22float2(*(const __half2*)&g);
            const float* c = &bond_s[(p >> 20) * EMBED + d0];
            a0.x += fmaxf(f.x + c[0], 0.f);
            a0.y += fmaxf(f.y + c[1], 0.f);
        }
        float inv = 1.0f / fmaxf((float)(re - rb), 1.0f);
        float2 hr = ((const float2*)hmast)[(size_t)v * 32 + sl];
        float2 t;
        t.x = (a0.x + a1.x + a2.x + a3.x) * inv + hr.x;
        t.y = (a0.y + a1.y + a2.y + a3.y) * inv + hr.y;
        ((float2*)t_out)[(size_t)v * 32 + sl] = t;
    }
}

// Streaming GEMM + BN column stats: h_pre = t @ W + b. 4 nodes per wave
// staged through LDS; each Ws read amortized over 4 nodes.
__launch_bounds__(256)
__global__ void gemm_kernel(const float* __restrict__ t_in,
                            const float* __restrict__ W,      // [64,64]
                            const float* __restrict__ bias,   // [64]
                            float* __restrict__ h_pre,
                            float* __restrict__ colsum,
                            float* __restrict__ colsq) {
    __shared__ float Ws[EMBED * EMBED];      // 16 KB
    __shared__ float tslab[4][4][EMBED];     // 4 KB; reused for BN reduction

    int lane = threadIdx.x & 63;
    int wblk = threadIdx.x >> 6;

    for (int i = threadIdx.x; i < EMBED * EMBED; i += 256) Ws[i] = W[i];
    __syncthreads();

    float bj = bias[lane];
    float lsum = 0.0f, lsq = 0.0f;

    int gwid = blockIdx.x * 4 + wblk;
    int nw   = gridDim.x * 4;

    for (int v0 = gwid * 4; v0 < N_NODES; v0 += nw * 4) {
#pragma unroll
        for (int k = 0; k < 4; ++k) {
            int v = v0 + k;
            tslab[wblk][k][lane] = (v < N_NODES) ? t_in[(size_t)v * EMBED + lane] : 0.0f;
        }

        float o0 = bj, o1 = bj, o2 = bj, o3 = bj;
#pragma unroll
        for (int dq = 0; dq < 16; ++dq) {
            float w0 = Ws[(dq * 4 + 0) * EMBED + lane];
            float w1 = Ws[(dq * 4 + 1) * EMBED + lane];
            float w2 = Ws[(dq * 4 + 2) * EMBED + lane];
            float w3 = Ws[(dq * 4 + 3) * EMBED + lane];
            float4 t0 = *(const float4*)&tslab[wblk][0][dq * 4];   // wave-uniform broadcast
            float4 t1 = *(const float4*)&tslab[wblk][1][dq * 4];
            float4 t2 = *(const float4*)&tslab[wblk][2][dq * 4];
            float4 t3 = *(const float4*)&tslab[wblk][3][dq * 4];
            o0 += t0.x * w0 + t0.y * w1 + t0.z * w2 + t0.w * w3;
            o1 += t1.x * w0 + t1.y * w1 + t1.z * w2 + t1.w * w3;
            o2 += t2.x * w0 + t2.y * w1 + t2.z * w2 + t2.w * w3;
            o3 += t3.x * w0 + t3.y * w1 + t3.z * w2 + t3.w * w3;
        }
        float oo[4] = {o0, o1, o2, o3};
#pragma unroll
        for (int k = 0; k < 4; ++k) {
            int vv = v0 + k;
            if (vv < N_NODES) {
                h_pre[(size_t)vv * EMBED + lane] = oo[k];
                lsum += oo[k];
                lsq  += oo[k] * oo[k];
            }
        }
    }

    __syncthreads();
    tslab[wblk][0][lane] = lsum;
    tslab[wblk][1][lane] = lsq;
    __syncthreads();
    if (wblk == 0) {
        float s = tslab[0][0][lane] + tslab[1][0][lane] + tslab[2][0][lane] + tslab[3][0][lane];
        float q = tslab[0][1][lane] + tslab[1][1][lane] + tslab[2][1][lane] + tslab[3][1][lane];
        atomicAdd(&colsum[lane], s);
        atomicAdd(&colsq[lane], q);
    }
}

// batchnorm + optional relu + residual; writes fp32 h and fp16 mirror
__global__ void bn_kernel(const float4* __restrict__ h_pre4,
                          const float* __restrict__ colsum,
                          const float* __restrict__ colsq,
                          const float* __restrict__ gamma,
                          const float* __restrict__ beta,
                          float4* __restrict__ h4,
                          __half* __restrict__ hh,
                          int do_relu) {
    int idx = blockIdx.x * blockDim.x + threadIdx.x;   // one float4
    if (idx >= N_NODES * 16) return;
    int q = idx & 15;            // dims 4q..4q+3
    const float invN = 1.0f / (float)N_NODES;
    float4 p = h_pre4[idx];
    float4 r = h4[idx];
    float o[4] = {p.x, p.y, p.z, p.w};
    float rr[4] = {r.x, r.y, r.z, r.w};
#pragma unroll
    for (int c = 0; c < 4; ++c) {
        int j = q * 4 + c;
        float mu  = colsum[j] * invN;
        float var = colsq[j] * invN - mu * mu;
        float inv = rsqrtf(var + BN_EPS);
        float y = (o[c] - mu) * inv * gamma[j] + beta[j];
        if (do_relu) y = fmaxf(y, 0.0f);
        o[c] = y + rr[c];
    }
    float4 res = {o[0], o[1], o[2], o[3]};
    h4[idx] = res;
    __half2 m0 = __floats2half2_rn(res.x, res.y);
    __half2 m1 = __floats2half2_rn(res.z, res.w);
    uint2 packed;
    packed.x = *(unsigned*)&m0;
    packed.y = *(unsigned*)&m1;
    ((uint2*)hh)[idx] = packed;
}

// one wave per graph: sequential coalesced mean over its node range (gid sorted)
__global__ void pool_kernel(const int* __restrict__ gstart,
                            const float* __restrict__ h,
                            float* __restrict__ gmean) {
    int g    = (blockIdx.x * blockDim.x + threadIdx.x) >> 6;
    int lane = threadIdx.x & 63;
    if (g >= N_GRAPHS) return;
    int b = gstart[g], e = gstart[g + 1];
    float s = 0.0f;
    for (int v = b; v < e; ++v) s += h[v * EMBED + lane];
    gmean[g * EMBED + lane] = s / fmaxf((float)(e - b), 1.0f);
}

// [1000,64] @ [64,128] + b, one block (128 threads) per graph
__global__ void pred_kernel(const float* __restrict__ gmean,
                            const float* __restrict__ W,   // [64,128]
                            const float* __restrict__ b,   // [128]
                            float* __restrict__ out) {
    __shared__ float gm[EMBED];
    int g = blockIdx.x;
    int j = threadIdx.x;  // 0..127
    if (j < EMBED) gm[j] = gmean[g * EMBED + j];
    __syncthreads();
    float acc = b[j];
#pragma unroll
    for (int d = 0; d < EMBED; ++d)
        acc += gm[d] * W[d * OUT_DIM + j];
    out[g * OUT_DIM + j] = acc;
}

// ---------------- launch ----------------

extern "C" void kernel_launch(void* const* d_in, const int* in_sizes, int n_in,
                              void* d_out, int out_size, void* d_ws, size_t ws_size,
                              hipStream_t stream) {
    const int*   nfeat      = (const int*)d_in[0];
    const int*   efeat      = (const int*)d_in[1];
    const int*   src        = (const int*)d_in[2];
    const int*   dst        = (const int*)d_in[3];
    const int*   gid        = (const int*)d_in[4];
    const float* atom_embed = (const float*)d_in[5];
    const float* bond_embed = (const float*)d_in[6];  // [3,5,64]
    const float* conv_W     = (const float*)d_in[7];  // [3,64,64]
    const float* conv_b     = (const float*)d_in[8];  // [3,64]
    const float* bn_gamma   = (const float*)d_in[9];  // [3,64]
    const float* bn_beta    = (const float*)d_in[10]; // [3,64]
    const float* pred_W     = (const float*)d_in[11]; // [64,128]
    const float* pred_b     = (const float*)d_in[12]; // [128]
    float* out = (float*)d_out;

    char* wsb = (char*)d_ws;
    float*    h      = (float*)wsb;                     wsb += (size_t)N_NODES * EMBED * 4;
    float*    h_pre  = (float*)wsb;                     wsb += (size_t)N_NODES * EMBED * 4;
    float*    t_buf  = (float*)wsb;                     wsb += (size_t)N_NODES * EMBED * 4;
    __half*   hh     = (__half*)wsb;                    wsb += (size_t)N_NODES * EMBED * 2;
    int*      deg    = (int*)wsb;                       wsb += (size_t)N_NODES * 4;
    int*      rowptr = (int*)wsb;                       wsb += (size_t)(N_NODES + 1) * 4;
    int*      cursor = (int*)wsb;                       wsb += (size_t)N_NODES * 4;
    int*      bsum   = (int*)wsb;                       wsb += (size_t)NBLK * 4;
    int*      bpre   = (int*)wsb;                       wsb += (size_t)NBLK * 4;
    unsigned* ebuf   = (unsigned*)wsb;                  wsb += (size_t)N_EDGES * 4;
    int*      gstart = (int*)wsb;                       wsb += (size_t)(N_GRAPHS + 1) * 4;
    float*    gmean  = (float*)wsb;                     wsb += (size_t)N_GRAPHS * EMBED * 4;
    float*    colsum = (float*)wsb;                     wsb += (size_t)3 * EMBED * 4;
    float*    colsq  = (float*)wsb;                     wsb += (size_t)3 * EMBED * 4;

    hipMemsetAsync(deg, 0, N_NODES * sizeof(int), stream);
    hipMemsetAsync(colsum, 0, 6 * EMBED * sizeof(float), stream);  // all 3 layers' stats

    embed_kernel<<<(N_NODES * 16 + 255) / 256, 256, 0, stream>>>(nfeat, atom_embed, (float4*)h, hh);
    deg_kernel<<<(N_EDGES + 255) / 256, 256, 0, stream>>>(dst, deg);
    scan1_kernel<<<NBLK, 256, 0, stream>>>(deg, bsum);
    scan2_kernel<<<1, 512, 0, stream>>>(bsum, bpre);
    scan3_kernel<<<NBLK, 256, 0, stream>>>(deg, bpre, rowptr, cursor);
    scatter_kernel<<<(N_EDGES + 255) / 256, 256, 0, stream>>>(src, dst, efeat, cursor, ebuf);
    gbound_kernel<<<(N_NODES + 256) / 256, 256, 0, stream>>>(gid, gstart);

    for (int i = 0; i < 3; ++i) {
        gather_kernel<<<2048, 256, 0, stream>>>(
            rowptr, ebuf, bond_embed + i * 5 * EMBED, hh, h, t_buf);
        gemm_kernel<<<1024, 256, 0, stream>>>(
            t_buf, conv_W + i * EMBED * EMBED, conv_b + i * EMBED,
            h_pre, colsum + i * EMBED, colsq + i * EMBED);
        bn_kernel<<<(N_NODES * 16 + 255) / 256, 256, 0, stream>>>(
            (const float4*)h_pre, colsum + i * EMBED, colsq + i * EMBED,
            bn_gamma + i * EMBED, bn_beta + i * EMBED,
            (float4*)h, hh, (i != 2) ? 1 : 0);
    }

    pool_kernel<<<(N_GRAPHS * 64 + 255) / 256, 256, 0, stream>>>(gstart, h, gmean);
    pred_kernel<<<N_GRAPHS, OUT_DIM, 0, stream>>>(gmean, pred_W, pred_b, out);
}